// Round 4
// baseline (467.105 us; speedup 1.0000x reference)
//
#include <hip/hip_runtime.h>
#include <cstddef>

namespace {
constexpr int kB = 4;
constexpr int kS = 4096;
constexpr int kD = 64;
constexpr float kC = 0.18033688011112042f;  // (1/8) * log2(e) : exp(s/8) = exp2(s*kC)

typedef float  f32x4  __attribute__((ext_vector_type(4)));
typedef __bf16 bf16x8 __attribute__((ext_vector_type(8)));
typedef short  s16x2  __attribute__((ext_vector_type(2)));
typedef short  s16x4  __attribute__((ext_vector_type(4)));
typedef short  s16x8  __attribute__((ext_vector_type(8)));
typedef int    i32x4  __attribute__((ext_vector_type(4)));

constexpr size_t kWsQ = (size_t)kB * kS * kD;         // elements (bf16/short)
constexpr size_t kWsNeed = 3 * kWsQ * sizeof(short);  // 6.29 MB
}

// __bf16 scalar is trivially copyable -> bit_cast legal. (__bf16)f rounds RNE.
__device__ __forceinline__ s16x2 pack_bf16(float a, float b) {
    __bf16 ha = (__bf16)a, hb = (__bf16)b;
    s16x2 r;
    r.x = __builtin_bit_cast(short, ha);
    r.y = __builtin_bit_cast(short, hb);
    return r;
}

// ============================ pre-pass ====================================
// blocks [0,256): Q -> bf16 row-major; [256,512): K -> bf16 row-major;
// [512,768): V -> bf16 TRANSPOSED per batch: vt[b][d][j]  (64 x 4096)
__global__ __launch_bounds__(256)
void prepass_kernel(const float* __restrict__ q, const float* __restrict__ k,
                    const float* __restrict__ v, short* __restrict__ qb,
                    short* __restrict__ kb, short* __restrict__ vt)
{
    __shared__ float lt[64][65];
    const int bid = blockIdx.x, tid = threadIdx.x;
    if (bid < 512) {
        const float* src = (bid < 256) ? q : k;
        short* dst = (bid < 256) ? qb : kb;
        const int base = (bid & 255) * 4096;
        #pragma unroll
        for (int c = 0; c < 4; ++c) {
            const int idx = base + c * 1024 + tid * 4;
            float4 f = *(const float4*)(src + idx);
            s16x4 o = __builtin_shufflevector(pack_bf16(f.x, f.y), pack_bf16(f.z, f.w), 0, 1, 2, 3);
            *(s16x4*)(dst + idx) = o;
        }
    } else {
        const int vb = bid - 512;
        const int b = vb >> 6, j0 = (vb & 63) * 64;
        const int r = tid >> 2, seg = tid & 3;
        const float* vrow = v + ((size_t)(b * kS) + j0 + r) * kD + seg * 16;
        #pragma unroll
        for (int u = 0; u < 4; ++u) {
            float4 f = *(const float4*)(vrow + 4 * u);
            lt[r][seg * 16 + 4 * u + 0] = f.x;
            lt[r][seg * 16 + 4 * u + 1] = f.y;
            lt[r][seg * 16 + 4 * u + 2] = f.z;
            lt[r][seg * 16 + 4 * u + 3] = f.w;
        }
        __syncthreads();
        const int d = r, js = seg * 16;
        short* drow = vt + ((size_t)(b * kD) + d) * kS + j0 + js;
        #pragma unroll
        for (int w = 0; w < 4; ++w) {
            s16x4 o = __builtin_shufflevector(
                pack_bf16(lt[js + 4 * w + 0][d], lt[js + 4 * w + 1][d]),
                pack_bf16(lt[js + 4 * w + 2][d], lt[js + 4 * w + 3][d]), 0, 1, 2, 3);
            *(s16x4*)(drow + 4 * w) = o;
        }
    }
}

// ============================ main MFMA kernel =============================
// Block = 512 thr (8 waves), 16 Q rows per block; wave w handles j-slice
// [w*512, (w+1)*512). Grid = 4 * 256 = 1024 blocks, ALL co-resident (4/CU).
//
// R3 change: attn rows are 16KB = a multiple of the HBM channel-interleave
// super-period, so channel = f(column) (rows contribute <=1 bit). With every
// wave marching jb sequentially and all blocks in lockstep, the device's
// instantaneous write footprint was only 8 of 64 column-granules -> ~12% of
// write channels -> the invariant ~1.4-1.5 TB/s seen in R0/R1/R2 regardless
// of store shape/occupancy. Fix: per-block ROTATION of the chunk order
// (rot = swz&7, uniform across co-resident blocks) so the union of active
// blocks covers all 64 column-granules at any instant.
__global__ __launch_bounds__(512, 8)
void attn_mfma_kernel(const short* __restrict__ qb, const short* __restrict__ kb,
                      const short* __restrict__ vt, float* __restrict__ outg,
                      float* __restrict__ attng)
{
    // Pool: loop-1 epilogue partials (7 waves x 16 x 68) UNION
    //       loop-2 staging (8 waves x 16 x 68). Disjoint in time.
    __shared__ __align__(16) float lds_pool[8 * 16 * 68];  // 34816 B
    __shared__ float lds_rs[8][16];   // partial row sums per wave
    __shared__ float lds_linv[16];    // NOT in pool: read after 2nd barrier

    // XCD swizzle: 1024 blocks % 8 XCDs == 0 -> bijective.
    const int swz = (blockIdx.x & 7) * 128 + (blockIdx.x >> 3);
    const int b  = swz >> 8;
    const int i0 = (swz & 255) * 16;
    const int lane = threadIdx.x & 63;
    const int wave = threadIdx.x >> 6;   // 0..7
    const int t = lane & 15;       // col index of C-tiles (Q-row)
    const int q = lane >> 4;       // quad

    const short* Qb = qb + ((size_t)(b * kS) + i0) * kD;
    const short* Kb = kb + (size_t)(b * kS) * kD;
    const short* Vt = vt + (size_t)b * kD * kS;

    // Q fragments: persistent across the whole kernel
    const bf16x8 qf0 = *(const bf16x8*)(Qb + t * kD + 8 * q);
    const bf16x8 qf1 = *(const bf16x8*)(Qb + t * kD + 32 + 8 * q);

    const int jbeg = wave * (kS / 8);
    const int jend = jbeg + (kS / 8);
    const int sA = t + 32 * (q & 1);  // shuffle source lane A (B = sA+16)

    f32x4 oacc[4];
    #pragma unroll
    for (int dt = 0; dt < 4; ++dt) oacc[dt] = (f32x4){0.f, 0.f, 0.f, 0.f};
    float rs = 0.f;

    // -------- loop 1: row sums + unnormalized P*V, 32 j's/iter, NO barriers
    for (int j0 = jbeg; j0 < jend; j0 += 32) {
        int p0 = 0, p1 = 0, p2 = 0, p3 = 0;
        #pragma unroll
        for (int h = 0; h < 2; ++h) {
            const short* p = Kb + (size_t)(j0 + 16 * h + t) * kD + 8 * q;
            const bf16x8 ka0 = *(const bf16x8*)p;
            const bf16x8 ka1 = *(const bf16x8*)(p + 32);
            f32x4 acc = (f32x4){0.f, 0.f, 0.f, 0.f};
            acc = __builtin_amdgcn_mfma_f32_16x16x32_bf16(ka0, qf0, acc, 0, 0, 0);
            acc = __builtin_amdgcn_mfma_f32_16x16x32_bf16(ka1, qf1, acc, 0, 0, 0);
            const float e0 = __builtin_amdgcn_exp2f(acc[0] * kC);
            const float e1 = __builtin_amdgcn_exp2f(acc[1] * kC);
            const float e2 = __builtin_amdgcn_exp2f(acc[2] * kC);
            const float e3 = __builtin_amdgcn_exp2f(acc[3] * kC);
            rs += (e0 + e1) + (e2 + e3);
            // lane holds P[i0+t][16h+4q+r]; pack and redistribute in-register
            const int d0 = __builtin_bit_cast(int, pack_bf16(e0, e1));
            const int d1 = __builtin_bit_cast(int, pack_bf16(e2, e3));
            const int a0 = __shfl(d0, sA);
            const int a1 = __shfl(d1, sA);
            const int b0 = __shfl(d0, sA + 16);
            const int b1 = __shfl(d1, sA + 16);
            if ((q >> 1) == h) { p0 = a0; p1 = a1; p2 = b0; p3 = b1; }
        }
        const i32x4 pi = (i32x4){p0, p1, p2, p3};
        const bf16x8 pa = __builtin_bit_cast(bf16x8, pi);

        // B-frags: V[j0+8q+j][dv=16dt+t] = vt[d=16dt+t][j0+8q+j]
        #pragma unroll
        for (int dt = 0; dt < 4; ++dt) {
            const bf16x8 vb = *(const bf16x8*)(Vt + (size_t)(16 * dt + t) * kS + j0 + 8 * q);
            oacc[dt] = __builtin_amdgcn_mfma_f32_16x16x32_bf16(pa, vb, oacc[dt], 0, 0, 0);
        }
    }

    // quad-reduce row sums: rs becomes this wave's full slice-sum for row i0+t
    rs += __shfl_xor(rs, 16);
    rs += __shfl_xor(rs, 32);

    // -------- combine the 8 j-slices through LDS (2 barriers total) --------
    if (lane < 16) lds_rs[wave][t] = rs;
    if (wave > 0) {
        #pragma unroll
        for (int dt = 0; dt < 4; ++dt)
            #pragma unroll
            for (int r = 0; r < 4; ++r)
                lds_pool[((wave - 1) * 16 + 4 * q + r) * 68 + 16 * dt + t] = oacc[dt][r];
    }
    __syncthreads();
    if (wave == 0) {
        #pragma unroll
        for (int w = 0; w < 7; ++w)
            #pragma unroll
            for (int dt = 0; dt < 4; ++dt)
                #pragma unroll
                for (int r = 0; r < 4; ++r)
                    oacc[dt][r] += lds_pool[(w * 16 + 4 * q + r) * 68 + 16 * dt + t];
        float tot = 0.f;
        #pragma unroll
        for (int w = 0; w < 8; ++w) tot += lds_rs[w][t];
        if (lane < 16) lds_linv[t] = 1.0f / tot;
    }
    __syncthreads();

    // out store (wave 0 only): lane holds out[i=i0+4q+r][dv=16dt+t]
    if (wave == 0) {
        #pragma unroll
        for (int r = 0; r < 4; ++r) {
            const float li = lds_linv[4 * q + r];
            float* orow = outg + ((size_t)(b * kS) + i0 + 4 * q + r) * kD + t;
            #pragma unroll
            for (int dt = 0; dt < 4; ++dt)
                orow[16 * dt] = oacc[dt][r] * li;
        }
    }
    const float li_t = lds_linv[t];  // normalizer for attn row i0+t

    // -------- loop 2: recompute scores, stage 16x64 tile in LDS, store -----
    float* stw = lds_pool + wave * (16 * 68);  // this wave's private staging
    const int srow = lane >> 4;        // 0..3: row-within-group for store
    const int scol = (lane & 15) * 4;  // 0..60: j-offset for store
    // per-store-phase base pointers (rows 4s+srow, col scol)
    float* abase0 = attng + ((size_t)(b * kS) + i0 + 0 + srow) * kS + scol;
    float* abase1 = attng + ((size_t)(b * kS) + i0 + 4 + srow) * kS + scol;
    float* abase2 = attng + ((size_t)(b * kS) + i0 + 8 + srow) * kS + scol;
    float* abase3 = attng + ((size_t)(b * kS) + i0 + 12 + srow) * kS + scol;

    const int rot = swz & 7;  // uniform over co-resident blocks
    for (int k = 0; k < 8; ++k) {
        const int jb = jbeg + (((k + rot) & 7) << 6);  // rotated 64-col chunk
        #pragma unroll
        for (int m = 0; m < 4; ++m) {
            const int j0 = jb + 16 * m;
            const short* p = Kb + (size_t)(j0 + t) * kD + 8 * q;
            const bf16x8 ka0 = *(const bf16x8*)p;
            const bf16x8 ka1 = *(const bf16x8*)(p + 32);
            f32x4 acc = (f32x4){0.f, 0.f, 0.f, 0.f};
            acc = __builtin_amdgcn_mfma_f32_16x16x32_bf16(ka0, qf0, acc, 0, 0, 0);
            acc = __builtin_amdgcn_mfma_f32_16x16x32_bf16(ka1, qf1, acc, 0, 0, 0);
            f32x4 o;
            o[0] = __builtin_amdgcn_exp2f(acc[0] * kC) * li_t;
            o[1] = __builtin_amdgcn_exp2f(acc[1] * kC) * li_t;
            o[2] = __builtin_amdgcn_exp2f(acc[2] * kC) * li_t;
            o[3] = __builtin_amdgcn_exp2f(acc[3] * kC) * li_t;
            // lane (t,q): row t, cols 16m+4q..+3 of this 64-j chunk
            *(f32x4*)&stw[t * 68 + 16 * m + 4 * q] = o;
        }
        // same-wave LDS RAW: compiler inserts lgkmcnt; no barrier needed.
        #pragma unroll
        for (int s = 0; s < 4; ++s) {
            const int row = 4 * s + srow;
            const f32x4 vld = *(const f32x4*)&stw[row * 68 + scol];
            float* dst = (s == 0 ? abase0 : s == 1 ? abase1 : s == 2 ? abase2 : abase3) + jb;
            // 16 lanes x 16B contiguous per row = 256B x 4 rows per instr
            __builtin_nontemporal_store(vld, (f32x4*)dst);
        }
    }
}

// ======================= fp32 fallback (R1 kernel, passed) =================
namespace fb {
constexpr int QT = 64, JT = 64;
constexpr float kScale = 0.125f;
constexpr int LP = kD + 4;
}
__global__ __launch_bounds__(256, 1)
void attn_fp32_kernel(const float* __restrict__ qg, const float* __restrict__ kg,
                      const float* __restrict__ vg, float* __restrict__ outg,
                      float* __restrict__ attng)
{
    using namespace fb;
    __shared__ float qs[QT][LP];
    __shared__ float ks[JT][LP];
    __shared__ float es[QT][JT + 4];
    __shared__ float red[QT][17];
    __shared__ float linv[QT];
    const int tid = threadIdx.x;
    const int tx = tid & 15, ty = tid >> 4;
    const int b = blockIdx.x >> 6, qt = blockIdx.x & 63, i0 = qt * QT;
    const float* qbp = qg + ((size_t)b * kS + i0) * kD;
    const float* kbase = kg + (size_t)b * kS * kD;
    const float* vbase = vg + (size_t)b * kS * kD;
    {
        const int r = tid >> 4, c4 = (tid & 15) * 4;
        #pragma unroll
        for (int m = 0; m < 4; ++m)
            *(float4*)&qs[r + 16 * m][c4] = *(const float4*)(qbp + (r + 16 * m) * kD + c4);
    }
    float oacc[4][4]; float rsv[4];
    #pragma unroll
    for (int r = 0; r < 4; ++r) { rsv[r] = 0.f; for (int c = 0; c < 4; ++c) oacc[r][c] = 0.f; }
    for (int jt = 0; jt < kS / JT; ++jt) {
        const float* kt = kbase + (size_t)(jt * JT) * kD;
        const int r = tid >> 4, c4 = (tid & 15) * 4;
        #pragma unroll
        for (int m = 0; m < 4; ++m)
            *(float4*)&ks[r + 16 * m][c4] = *(const float4*)(kt + (r + 16 * m) * kD + c4);
        __syncthreads();
        float acc[4][4] = {{0.f}};
        #pragma unroll
        for (int d4 = 0; d4 < kD / 4; ++d4) {
            float4 qa[4], kav[4];
            #pragma unroll
            for (int r2 = 0; r2 < 4; ++r2) qa[r2] = *(const float4*)&qs[ty * 4 + r2][d4 * 4];
            #pragma unroll
            for (int c = 0; c < 4; ++c) kav[c] = *(const float4*)&ks[tx * 4 + c][d4 * 4];
            #pragma unroll
            for (int r2 = 0; r2 < 4; ++r2)
                #pragma unroll
                for (int c = 0; c < 4; ++c)
                    acc[r2][c] += qa[r2].x * kav[c].x + qa[r2].y * kav[c].y
                                + qa[r2].z * kav[c].z + qa[r2].w * kav[c].w;
        }
        #pragma unroll
        for (int r2 = 0; r2 < 4; ++r2) {
            float4 e4;
            e4.x = __expf(acc[r2][0] * kScale); e4.y = __expf(acc[r2][1] * kScale);
            e4.z = __expf(acc[r2][2] * kScale); e4.w = __expf(acc[r2][3] * kScale);
            rsv[r2] += (e4.x + e4.y) + (e4.z + e4.w);
            *(float4*)&es[ty * 4 + r2][tx * 4] = e4;
        }
        __syncthreads();
        const float* vt2 = vbase + (size_t)(jt * JT) * kD;
        #pragma unroll 4
        for (int j4 = 0; j4 < JT / 4; ++j4) {
            float4 vv[4], ea[4];
            #pragma unroll
            for (int n = 0; n < 4; ++n) vv[n] = *(const float4*)(vt2 + (size_t)(j4 * 4 + n) * kD + tx * 4);
            #pragma unroll
            for (int r2 = 0; r2 < 4; ++r2) ea[r2] = *(const float4*)&es[ty * 4 + r2][j4 * 4];
            #pragma unroll
            for (int r2 = 0; r2 < 4; ++r2) {
                oacc[r2][0] += ea[r2].x * vv[0].x + ea[r2].y * vv[1].x + ea[r2].z * vv[2].x + ea[r2].w * vv[3].x;
                oacc[r2][1] += ea[r2].x * vv[0].y + ea[r2].y * vv[1].y + ea[r2].z * vv[2].y + ea[r2].w * vv[3].y;
                oacc[r2][2] += ea[r2].x * vv[0].z + ea[r2].y * vv[1].z + ea[r2].z * vv[2].z + ea[r2].w * vv[3].z;
                oacc[r2][3] += ea[r2].x * vv[0].w + ea[r2].y * vv[1].w + ea[r2].z * vv[2].w + ea[r2].w * vv[3].w;
            }
        }
        __syncthreads();
    }
    #pragma unroll
    for (int r = 0; r < 4; ++r) red[ty * 4 + r][tx] = rsv[r];
    __syncthreads();
    if (tid < QT) {
        float s = 0.f;
        #pragma unroll
        for (int t2 = 0; t2 < 16; ++t2) s += red[tid][t2];
        linv[tid] = 1.0f / s;
    }
    __syncthreads();
    {
        float* ob = outg + ((size_t)b * kS + i0) * kD;
        #pragma unroll
        for (int r = 0; r < 4; ++r) {
            const int i = ty * 4 + r; const float li = linv[i];
            float4 o4; o4.x = oacc[r][0] * li; o4.y = oacc[r][1] * li;
            o4.z = oacc[r][2] * li; o4.w = oacc[r][3] * li;
            *(float4*)(ob + (size_t)i * kD + tx * 4) = o4;
        }
    }
    float* ab = attng + ((size_t)b * kS + i0) * kS;
    for (int jt = 0; jt < kS / JT; ++jt) {
        const float* kt = kbase + (size_t)(jt * JT) * kD;
        const int r = tid >> 4, c4 = (tid & 15) * 4;
        #pragma unroll
        for (int m = 0; m < 4; ++m)
            *(float4*)&ks[r + 16 * m][c4] = *(const float4*)(kt + (r + 16 * m) * kD + c4);
        __syncthreads();
        float acc[4][4] = {{0.f}};
        #pragma unroll
        for (int d4 = 0; d4 < kD / 4; ++d4) {
            float4 qa[4], kav[4];
            #pragma unroll
            for (int r2 = 0; r2 < 4; ++r2) qa[r2] = *(const float4*)&qs[ty * 4 + r2][d4 * 4];
            #pragma unroll
            for (int c = 0; c < 4; ++c) kav[c] = *(const float4*)&ks[tx * 4 + c][d4 * 4];
            #pragma unroll
            for (int r2 = 0; r2 < 4; ++r2)
                #pragma unroll
                for (int c = 0; c < 4; ++c)
                    acc[r2][c] += qa[r2].x * kav[c].x + qa[r2].y * kav[c].y
                                + qa[r2].z * kav[c].z + qa[r2].w * kav[c].w;
        }
        #pragma unroll
        for (int r2 = 0; r2 < 4; ++r2) {
            const int i = ty * 4 + r2; const float li = linv[i];
            float4 e4;
            e4.x = __expf(acc[r2][0] * kScale) * li; e4.y = __expf(acc[r2][1] * kScale) * li;
            e4.z = __expf(acc[r2][2] * kScale) * li; e4.w = __expf(acc[r2][3] * kScale) * li;
            *(float4*)(ab + (size_t)i * kS + jt * JT + tx * 4) = e4;
        }
        __syncthreads();
    }
}

extern "C" void kernel_launch(void* const* d_in, const int* in_sizes, int n_in,
                              void* d_out, int out_size, void* d_ws, size_t ws_size,
                              hipStream_t stream) {
    const float* q = (const float*)d_in[0];
    const float* k = (const float*)d_in[1];
    const float* v = (const float*)d_in[2];
    float* out  = (float*)d_out;                  // [4,4096,64]
    float* attn = out + (size_t)kB * kS * kD;     // [4,4096,4096]

    if (ws_size >= kWsNeed) {
        short* qb = (short*)d_ws;
        short* kbp = qb + kWsQ;
        short* vt = kbp + kWsQ;
        prepass_kernel<<<dim3(768), 256, 0, stream>>>(q, k, v, qb, kbp, vt);
        attn_mfma_kernel<<<dim3(kB * (kS / 16)), 512, 0, stream>>>(qb, kbp, vt, out, attn);
    } else {
        attn_fp32_kernel<<<dim3(kB * (kS / 64)), 256, 0, stream>>>(q, k, v, out, attn);
    }
}

// Round 6
// 423.439 us; speedup vs baseline: 1.1031x; 1.1031x over previous
//
#include <hip/hip_runtime.h>
#include <cstddef>

namespace {
constexpr int kB = 4;
constexpr int kS = 4096;
constexpr int kD = 64;
constexpr float kC = 0.18033688011112042f;  // (1/8) * log2(e) : exp(s/8) = exp2(s*kC)

typedef float  f32x4  __attribute__((ext_vector_type(4)));
typedef __bf16 bf16x8 __attribute__((ext_vector_type(8)));
typedef short  s16x2  __attribute__((ext_vector_type(2)));
typedef short  s16x4  __attribute__((ext_vector_type(4)));
typedef short  s16x8  __attribute__((ext_vector_type(8)));
typedef int    i32x4  __attribute__((ext_vector_type(4)));

constexpr size_t kWsQ = (size_t)kB * kS * kD;         // elements (bf16/short)
constexpr size_t kWsLinv = (size_t)kB * kS;           // floats
// qb + kb + vt (bf16) + linv (f32)
constexpr size_t kWsNeed = 3 * kWsQ * sizeof(short) + kWsLinv * sizeof(float);
}

// __bf16 scalar is trivially copyable -> bit_cast legal. (__bf16)f rounds RNE.
__device__ __forceinline__ s16x2 pack_bf16(float a, float b) {
    __bf16 ha = (__bf16)a, hb = (__bf16)b;
    s16x2 r;
    r.x = __builtin_bit_cast(short, ha);
    r.y = __builtin_bit_cast(short, hb);
    return r;
}

// ============================ pre-pass ====================================
// blocks [0,256): Q -> bf16 row-major; [256,512): K -> bf16 row-major;
// [512,768): V -> bf16 TRANSPOSED per batch: vt[b][d][j]  (64 x 4096)
__global__ __launch_bounds__(256)
void prepass_kernel(const float* __restrict__ q, const float* __restrict__ k,
                    const float* __restrict__ v, short* __restrict__ qb,
                    short* __restrict__ kb, short* __restrict__ vt)
{
    __shared__ float lt[64][65];
    const int bid = blockIdx.x, tid = threadIdx.x;
    if (bid < 512) {
        const float* src = (bid < 256) ? q : k;
        short* dst = (bid < 256) ? qb : kb;
        const int base = (bid & 255) * 4096;
        #pragma unroll
        for (int c = 0; c < 4; ++c) {
            const int idx = base + c * 1024 + tid * 4;
            float4 f = *(const float4*)(src + idx);
            s16x4 o = __builtin_shufflevector(pack_bf16(f.x, f.y), pack_bf16(f.z, f.w), 0, 1, 2, 3);
            *(s16x4*)(dst + idx) = o;
        }
    } else {
        const int vb = bid - 512;
        const int b = vb >> 6, j0 = (vb & 63) * 64;
        const int r = tid >> 2, seg = tid & 3;
        const float* vrow = v + ((size_t)(b * kS) + j0 + r) * kD + seg * 16;
        #pragma unroll
        for (int u = 0; u < 4; ++u) {
            float4 f = *(const float4*)(vrow + 4 * u);
            lt[r][seg * 16 + 4 * u + 0] = f.x;
            lt[r][seg * 16 + 4 * u + 1] = f.y;
            lt[r][seg * 16 + 4 * u + 2] = f.z;
            lt[r][seg * 16 + 4 * u + 3] = f.w;
        }
        __syncthreads();
        const int d = r, js = seg * 16;
        short* drow = vt + ((size_t)(b * kD) + d) * kS + j0 + js;
        #pragma unroll
        for (int w = 0; w < 4; ++w) {
            s16x4 o = __builtin_shufflevector(
                pack_bf16(lt[js + 4 * w + 0][d], lt[js + 4 * w + 1][d]),
                pack_bf16(lt[js + 4 * w + 2][d], lt[js + 4 * w + 3][d]), 0, 1, 2, 3);
            *(s16x4*)(drow + 4 * w) = o;
        }
    }
}

// ===================== kernel A: PV pass (R2 loop 1) =======================
// Block = 512 thr (8 waves), 16 Q rows; wave w handles j-slice [w*512,...).
// Computes out[b,i,:] and linv[b,i] (row-sum reciprocal) to workspace.
// R5/R6: split from the store pass so rocprof reports per-phase durations —
// three store-side theories (occupancy, coalescing, channel rotation) all
// failed to move the invariant ~200 µs; ablation before further tuning.
__global__ __launch_bounds__(512, 8)
void attn_pv_kernel(const short* __restrict__ qb, const short* __restrict__ kb,
                    const short* __restrict__ vt, float* __restrict__ outg,
                    float* __restrict__ linv_ws)
{
    __shared__ __align__(16) float lds_out[7][16][68];
    __shared__ float lds_rs[8][16];   // partial row sums per wave
    __shared__ float lds_linv[16];

    // XCD swizzle: 1024 blocks % 8 XCDs == 0 -> bijective.
    const int swz = (blockIdx.x & 7) * 128 + (blockIdx.x >> 3);
    const int b  = swz >> 8;
    const int i0 = (swz & 255) * 16;
    const int lane = threadIdx.x & 63;
    const int wave = threadIdx.x >> 6;   // 0..7
    const int t = lane & 15;       // col index of C-tiles (Q-row)
    const int q = lane >> 4;       // quad

    const short* Qb = qb + ((size_t)(b * kS) + i0) * kD;
    const short* Kb = kb + (size_t)(b * kS) * kD;
    const short* Vt = vt + (size_t)b * kD * kS;

    const bf16x8 qf0 = *(const bf16x8*)(Qb + t * kD + 8 * q);
    const bf16x8 qf1 = *(const bf16x8*)(Qb + t * kD + 32 + 8 * q);

    const int jbeg = wave * (kS / 8);
    const int jend = jbeg + (kS / 8);
    const int sA = t + 32 * (q & 1);  // shuffle source lane A (B = sA+16)

    f32x4 oacc[4];
    #pragma unroll
    for (int dt = 0; dt < 4; ++dt) oacc[dt] = (f32x4){0.f, 0.f, 0.f, 0.f};
    float rs = 0.f;

    // -------- row sums + unnormalized P*V, 32 j's/iter, NO barriers --------
    for (int j0 = jbeg; j0 < jend; j0 += 32) {
        int p0 = 0, p1 = 0, p2 = 0, p3 = 0;
        #pragma unroll
        for (int h = 0; h < 2; ++h) {
            const short* p = Kb + (size_t)(j0 + 16 * h + t) * kD + 8 * q;
            const bf16x8 ka0 = *(const bf16x8*)p;
            const bf16x8 ka1 = *(const bf16x8*)(p + 32);
            f32x4 acc = (f32x4){0.f, 0.f, 0.f, 0.f};
            acc = __builtin_amdgcn_mfma_f32_16x16x32_bf16(ka0, qf0, acc, 0, 0, 0);
            acc = __builtin_amdgcn_mfma_f32_16x16x32_bf16(ka1, qf1, acc, 0, 0, 0);
            const float e0 = __builtin_amdgcn_exp2f(acc[0] * kC);
            const float e1 = __builtin_amdgcn_exp2f(acc[1] * kC);
            const float e2 = __builtin_amdgcn_exp2f(acc[2] * kC);
            const float e3 = __builtin_amdgcn_exp2f(acc[3] * kC);
            rs += (e0 + e1) + (e2 + e3);
            // lane holds P[i0+t][16h+4q+r]; pack and redistribute in-register
            const int d0 = __builtin_bit_cast(int, pack_bf16(e0, e1));
            const int d1 = __builtin_bit_cast(int, pack_bf16(e2, e3));
            const int a0 = __shfl(d0, sA);
            const int a1 = __shfl(d1, sA);
            const int b0 = __shfl(d0, sA + 16);
            const int b1 = __shfl(d1, sA + 16);
            if ((q >> 1) == h) { p0 = a0; p1 = a1; p2 = b0; p3 = b1; }
        }
        const i32x4 pi = (i32x4){p0, p1, p2, p3};
        const bf16x8 pa = __builtin_bit_cast(bf16x8, pi);

        // B-frags: V[j0+8q+j][dv=16dt+t] = vt[d=16dt+t][j0+8q+j]
        #pragma unroll
        for (int dt = 0; dt < 4; ++dt) {
            const bf16x8 vb = *(const bf16x8*)(Vt + (size_t)(16 * dt + t) * kS + j0 + 8 * q);
            oacc[dt] = __builtin_amdgcn_mfma_f32_16x16x32_bf16(pa, vb, oacc[dt], 0, 0, 0);
        }
    }

    // quad-reduce row sums: rs becomes this wave's full slice-sum for row i0+t
    rs += __shfl_xor(rs, 16);
    rs += __shfl_xor(rs, 32);

    // -------- combine the 8 j-slices through LDS (2 barriers total) --------
    if (lane < 16) lds_rs[wave][t] = rs;
    if (wave > 0) {
        #pragma unroll
        for (int dt = 0; dt < 4; ++dt)
            #pragma unroll
            for (int r = 0; r < 4; ++r)
                lds_out[wave - 1][4 * q + r][16 * dt + t] = oacc[dt][r];
    }
    __syncthreads();
    if (wave == 0) {
        #pragma unroll
        for (int w = 0; w < 7; ++w)
            #pragma unroll
            for (int dt = 0; dt < 4; ++dt)
                #pragma unroll
                for (int r = 0; r < 4; ++r)
                    oacc[dt][r] += lds_out[w][4 * q + r][16 * dt + t];
        float tot = 0.f;
        #pragma unroll
        for (int w = 0; w < 8; ++w) tot += lds_rs[w][t];
        if (lane < 16) {
            const float li = 1.0f / tot;
            lds_linv[t] = li;
            linv_ws[(size_t)(b * kS) + i0 + t] = li;  // publish for kernel B
        }
    }
    __syncthreads();

    // out store (wave 0 only): lane holds out[i=i0+4q+r][dv=16dt+t]
    if (wave == 0) {
        #pragma unroll
        for (int r = 0; r < 4; ++r) {
            const float li = lds_linv[4 * q + r];
            float* orow = outg + ((size_t)(b * kS) + i0 + 4 * q + r) * kD + t;
            #pragma unroll
            for (int dt = 0; dt < 4; ++dt)
                orow[16 * dt] = oacc[dt][r] * li;
        }
    }
}

// ===================== kernel B: attn store pass (R2 loop 2) ===============
// Recompute scores, normalize with linv from workspace, stage each wave's
// 16x64 f32 tile in private LDS (no barriers), store 4 x 256B nt segments.
// Sequential chunk order (R4 rotation regressed: broke L2 K-sharing).
__global__ __launch_bounds__(512, 8)
void attn_store_kernel(const short* __restrict__ qb, const short* __restrict__ kb,
                       const float* __restrict__ linv_ws, float* __restrict__ attng)
{
    __shared__ __align__(16) float stg[8][16][68];  // 34816 B

    const int swz = (blockIdx.x & 7) * 128 + (blockIdx.x >> 3);
    const int b  = swz >> 8;
    const int i0 = (swz & 255) * 16;
    const int lane = threadIdx.x & 63;
    const int wave = threadIdx.x >> 6;   // 0..7
    const int t = lane & 15;
    const int q = lane >> 4;

    const short* Qb = qb + ((size_t)(b * kS) + i0) * kD;
    const short* Kb = kb + (size_t)(b * kS) * kD;

    const bf16x8 qf0 = *(const bf16x8*)(Qb + t * kD + 8 * q);
    const bf16x8 qf1 = *(const bf16x8*)(Qb + t * kD + 32 + 8 * q);

    const int jbeg = wave * (kS / 8);
    const int jend = jbeg + (kS / 8);

    const float li_t = linv_ws[(size_t)(b * kS) + i0 + t];

    float* stw = &stg[wave][0][0];     // this wave's private staging
    const int srow = lane >> 4;        // 0..3: row-within-group for store
    const int scol = (lane & 15) * 4;  // 0..60: j-offset for store
    float* abase0 = attng + ((size_t)(b * kS) + i0 + 0 + srow) * kS + scol;
    float* abase1 = attng + ((size_t)(b * kS) + i0 + 4 + srow) * kS + scol;
    float* abase2 = attng + ((size_t)(b * kS) + i0 + 8 + srow) * kS + scol;
    float* abase3 = attng + ((size_t)(b * kS) + i0 + 12 + srow) * kS + scol;

    for (int jb = jbeg; jb < jend; jb += 64) {
        #pragma unroll
        for (int m = 0; m < 4; ++m) {
            const int j0 = jb + 16 * m;
            const short* p = Kb + (size_t)(j0 + t) * kD + 8 * q;
            const bf16x8 ka0 = *(const bf16x8*)p;
            const bf16x8 ka1 = *(const bf16x8*)(p + 32);
            f32x4 acc = (f32x4){0.f, 0.f, 0.f, 0.f};
            acc = __builtin_amdgcn_mfma_f32_16x16x32_bf16(ka0, qf0, acc, 0, 0, 0);
            acc = __builtin_amdgcn_mfma_f32_16x16x32_bf16(ka1, qf1, acc, 0, 0, 0);
            f32x4 o;
            o[0] = __builtin_amdgcn_exp2f(acc[0] * kC) * li_t;
            o[1] = __builtin_amdgcn_exp2f(acc[1] * kC) * li_t;
            o[2] = __builtin_amdgcn_exp2f(acc[2] * kC) * li_t;
            o[3] = __builtin_amdgcn_exp2f(acc[3] * kC) * li_t;
            // lane (t,q): row t, cols 16m+4q..+3 of this 64-j chunk
            *(f32x4*)&stw[t * 68 + 16 * m + 4 * q] = o;
        }
        // same-wave LDS RAW: compiler inserts lgkmcnt; no barrier needed.
        #pragma unroll
        for (int s = 0; s < 4; ++s) {
            const int row = 4 * s + srow;
            const f32x4 vld = *(const f32x4*)&stw[row * 68 + scol];
            float* dst = (s == 0 ? abase0 : s == 1 ? abase1 : s == 2 ? abase2 : abase3) + jb;
            // 16 lanes x 16B contiguous per row = 256B x 4 rows per instr
            __builtin_nontemporal_store(vld, (f32x4*)dst);
        }
    }
}

// ======================= fp32 fallback (R1 kernel, passed) =================
namespace fb {
constexpr int QT = 64, JT = 64;
constexpr float kScale = 0.125f;
constexpr int LP = kD + 4;
}
__global__ __launch_bounds__(256, 1)
void attn_fp32_kernel(const float* __restrict__ qg, const float* __restrict__ kg,
                      const float* __restrict__ vg, float* __restrict__ outg,
                      float* __restrict__ attng)
{
    using namespace fb;
    __shared__ float qs[QT][LP];
    __shared__ float ks[JT][LP];
    __shared__ float es[QT][JT + 4];
    __shared__ float red[QT][17];
    __shared__ float linv[QT];
    const int tid = threadIdx.x;
    const int tx = tid & 15, ty = tid >> 4;
    const int b = blockIdx.x >> 6, qt = blockIdx.x & 63, i0 = qt * QT;
    const float* qbp = qg + ((size_t)b * kS + i0) * kD;
    const float* kbase = kg + (size_t)b * kS * kD;
    const float* vbase = vg + (size_t)b * kS * kD;
    {
        const int r = tid >> 4, c4 = (tid & 15) * 4;
        #pragma unroll
        for (int m = 0; m < 4; ++m)
            *(float4*)&qs[r + 16 * m][c4] = *(const float4*)(qbp + (r + 16 * m) * kD + c4);
    }
    float oacc[4][4]; float rsv[4];
    #pragma unroll
    for (int r = 0; r < 4; ++r) { rsv[r] = 0.f; for (int c = 0; c < 4; ++c) oacc[r][c] = 0.f; }
    for (int jt = 0; jt < kS / JT; ++jt) {
        const float* kt = kbase + (size_t)(jt * JT) * kD;
        const int r = tid >> 4, c4 = (tid & 15) * 4;
        #pragma unroll
        for (int m = 0; m < 4; ++m)
            *(float4*)&ks[r + 16 * m][c4] = *(const float4*)(kt + (r + 16 * m) * kD + c4);
        __syncthreads();
        float acc[4][4] = {{0.f}};
        #pragma unroll
        for (int d4 = 0; d4 < kD / 4; ++d4) {
            float4 qa[4], kav[4];
            #pragma unroll
            for (int r2 = 0; r2 < 4; ++r2) qa[r2] = *(const float4*)&qs[ty * 4 + r2][d4 * 4];
            #pragma unroll
            for (int c = 0; c < 4; ++c) kav[c] = *(const float4*)&ks[tx * 4 + c][d4 * 4];
            #pragma unroll
            for (int r2 = 0; r2 < 4; ++r2)
                #pragma unroll
                for (int c = 0; c < 4; ++c)
                    acc[r2][c] += qa[r2].x * kav[c].x + qa[r2].y * kav[c].y
                                + qa[r2].z * kav[c].z + qa[r2].w * kav[c].w;
        }
        #pragma unroll
        for (int r2 = 0; r2 < 4; ++r2) {
            float4 e4;
            e4.x = __expf(acc[r2][0] * kScale); e4.y = __expf(acc[r2][1] * kScale);
            e4.z = __expf(acc[r2][2] * kScale); e4.w = __expf(acc[r2][3] * kScale);
            rsv[r2] += (e4.x + e4.y) + (e4.z + e4.w);
            *(float4*)&es[ty * 4 + r2][tx * 4] = e4;
        }
        __syncthreads();
        const float* vt2 = vbase + (size_t)(jt * JT) * kD;
        #pragma unroll 4
        for (int j4 = 0; j4 < JT / 4; ++j4) {
            float4 vv[4], ea[4];
            #pragma unroll
            for (int n = 0; n < 4; ++n) vv[n] = *(const float4*)(vt2 + (size_t)(j4 * 4 + n) * kD + tx * 4);
            #pragma unroll
            for (int r2 = 0; r2 < 4; ++r2) ea[r2] = *(const float4*)&es[ty * 4 + r2][j4 * 4];
            #pragma unroll
            for (int r2 = 0; r2 < 4; ++r2) {
                oacc[r2][0] += ea[r2].x * vv[0].x + ea[r2].y * vv[1].x + ea[r2].z * vv[2].x + ea[r2].w * vv[3].x;
                oacc[r2][1] += ea[r2].x * vv[0].y + ea[r2].y * vv[1].y + ea[r2].z * vv[2].y + ea[r2].w * vv[3].y;
                oacc[r2][2] += ea[r2].x * vv[0].z + ea[r2].y * vv[1].z + ea[r2].z * vv[2].z + ea[r2].w * vv[3].z;
                oacc[r2][3] += ea[r2].x * vv[0].w + ea[r2].y * vv[1].w + ea[r2].z * vv[2].w + ea[r2].w * vv[3].w;
            }
        }
        __syncthreads();
    }
    #pragma unroll
    for (int r = 0; r < 4; ++r) red[ty * 4 + r][tx] = rsv[r];
    __syncthreads();
    if (tid < QT) {
        float s = 0.f;
        #pragma unroll
        for (int t2 = 0; t2 < 16; ++t2) s += red[tid][t2];
        linv[tid] = 1.0f / s;
    }
    __syncthreads();
    {
        float* ob = outg + ((size_t)b * kS + i0) * kD;
        #pragma unroll
        for (int r = 0; r < 4; ++r) {
            const int i = ty * 4 + r; const float li = linv[i];
            float4 o4; o4.x = oacc[r][0] * li; o4.y = oacc[r][1] * li;
            o4.z = oacc[r][2] * li; o4.w = oacc[r][3] * li;
            *(float4*)(ob + (size_t)i * kD + tx * 4) = o4;
        }
    }
    float* ab = attng + ((size_t)b * kS + i0) * kS;
    for (int jt = 0; jt < kS / JT; ++jt) {
        const float* kt = kbase + (size_t)(jt * JT) * kD;
        const int r = tid >> 4, c4 = (tid & 15) * 4;
        #pragma unroll
        for (int m = 0; m < 4; ++m)
            *(float4*)&ks[r + 16 * m][c4] = *(const float4*)(kt + (r + 16 * m) * kD + c4);
        __syncthreads();
        float acc[4][4] = {{0.f}};
        #pragma unroll
        for (int d4 = 0; d4 < kD / 4; ++d4) {
            float4 qa[4], kav[4];
            #pragma unroll
            for (int r2 = 0; r2 < 4; ++r2) qa[r2] = *(const float4*)&qs[ty * 4 + r2][d4 * 4];
            #pragma unroll
            for (int c = 0; c < 4; ++c) kav[c] = *(const float4*)&ks[tx * 4 + c][d4 * 4];
            #pragma unroll
            for (int r2 = 0; r2 < 4; ++r2)
                #pragma unroll
                for (int c = 0; c < 4; ++c)
                    acc[r2][c] += qa[r2].x * kav[c].x + qa[r2].y * kav[c].y
                                + qa[r2].z * kav[c].z + qa[r2].w * kav[c].w;
        }
        #pragma unroll
        for (int r2 = 0; r2 < 4; ++r2) {
            const int i = ty * 4 + r2; const float li = linv[i];
            float4 e4;
            e4.x = __expf(acc[r2][0] * kScale) * li; e4.y = __expf(acc[r2][1] * kScale) * li;
            e4.z = __expf(acc[r2][2] * kScale) * li; e4.w = __expf(acc[r2][3] * kScale) * li;
            *(float4*)(ab + (size_t)i * kS + jt * JT + tx * 4) = e4;
        }
        __syncthreads();
    }
}

extern "C" void kernel_launch(void* const* d_in, const int* in_sizes, int n_in,
                              void* d_out, int out_size, void* d_ws, size_t ws_size,
                              hipStream_t stream) {
    const float* q = (const float*)d_in[0];
    const float* k = (const float*)d_in[1];
    const float* v = (const float*)d_in[2];
    float* out  = (float*)d_out;                  // [4,4096,64]
    float* attn = out + (size_t)kB * kS * kD;     // [4,4096,4096]

    if (ws_size >= kWsNeed) {
        short* qb = (short*)d_ws;
        short* kbp = qb + kWsQ;
        short* vt = kbp + kWsQ;
        float* linv_ws = (float*)(vt + kWsQ);
        prepass_kernel<<<dim3(768), 256, 0, stream>>>(q, k, v, qb, kbp, vt);
        attn_pv_kernel<<<dim3(kB * (kS / 16)), 512, 0, stream>>>(qb, kbp, vt, out, linv_ws);
        attn_store_kernel<<<dim3(kB * (kS / 16)), 512, 0, stream>>>(qb, kbp, linv_ws, attn);
    } else {
        attn_fp32_kernel<<<dim3(kB * (kS / 64)), 256, 0, stream>>>(q, k, v, out, attn);
    }
}